// Round 1
// baseline (235.352 us; speedup 1.0000x reference)
//
#include <hip/hip_runtime.h>

// DCNv2 forward, MI355X (gfx950).
// Pipeline:
//  k_transpose: x NCHW f32 -> x_bf NHWC bf16
//  k_repack:    w_off (27,256,3,3)  -> wrep  [32][kk*256+c] bf16 (oc padded to 32)
//               dcn_w (256,256,3,3) -> wmain [256][kk*256+c] bf16
//  k_offconv:   MFMA GEMM, implicit im2col from x_bf -> om[r][32] f32 (bias+sigmoid applied)
//  k_sample:    bilinear gather * mask -> col[r][2304] bf16
//  k_gemm:      MFMA GEMM col x wmain^T -> out (N,256,64,64) f32

typedef __bf16 bf16x8 __attribute__((ext_vector_type(8)));
typedef float  f32x4  __attribute__((ext_vector_type(4)));

// workspace layout (bytes, all 16B aligned)
#define XBF_OFF   0u            // 4*4096*256*2  = 8,388,608
#define WREP_OFF  8388608u      // 32*2304*2     =   147,456
#define WMAIN_OFF 8536064u      // 256*2304*2    = 1,179,648
#define OM_OFF    9715712u      // 16384*32*4    = 2,097,152
#define COL_OFF   11812864u     // 16384*2304*2  = 75,497,472  (total ~87.3 MB)

__device__ __forceinline__ unsigned short f2bf(float f) {
  unsigned int u = __float_as_uint(f);
  u += 0x7fffu + ((u >> 16) & 1u);          // round-to-nearest-even
  return (unsigned short)(u >> 16);
}
__device__ __forceinline__ float bf2f(unsigned short h) {
  return __uint_as_float(((unsigned int)h) << 16);
}

// ---------------- x NCHW -> NHWC bf16 ----------------
__global__ __launch_bounds__(256) void k_transpose(const float* __restrict__ x,
                                                   unsigned short* __restrict__ xbf) {
  __shared__ float tile[32][65];
  int n  = blockIdx.z;
  int cb = blockIdx.y;   // 0..7  -> c0 = cb*32
  int xb = blockIdx.x;   // 0..63 -> yx0 = xb*64
  int t  = threadIdx.x;
  int xx  = t & 63;
  int cc0 = t >> 6;      // 0..3
#pragma unroll
  for (int j = 0; j < 8; ++j) {
    int cc = cc0 + j * 4;
    tile[cc][xx] = x[((size_t)(n * 256 + cb * 32 + cc) << 12) + xb * 64 + xx];
  }
  __syncthreads();
  int ccw = t & 31;
  int xw0 = t >> 5;      // 0..7
#pragma unroll
  for (int j = 0; j < 8; ++j) {
    int xw = xw0 + j * 8;
    xbf[((size_t)((n << 12) + xb * 64 + xw)) * 256 + cb * 32 + ccw] = f2bf(tile[ccw][xw]);
  }
}

// ---------------- weight repack [oc][c*9+kk] -> [oc][kk*256+c] bf16 ----------------
__global__ __launch_bounds__(256) void k_repack(const float* __restrict__ w,
                                                unsigned short* __restrict__ wout,
                                                int OCin, int OCout) {
  int idx = blockIdx.x * 256 + threadIdx.x;
  int total = OCout * 2304;
  if (idx >= total) return;
  int oc  = idx / 2304;
  int rem = idx - oc * 2304;
  int kk  = rem >> 8;
  int c   = rem & 255;
  float v = (oc < OCin) ? w[oc * 2304 + c * 9 + kk] : 0.f;
  wout[idx] = f2bf(v);
}

// ---------------- offset-field conv: implicit-im2col MFMA GEMM ----------------
// om[r][oc], r = n*4096 + oy*64 + ox, oc in [0,32). M-tile=64 (one image row), N=32, K=2304.
__global__ __launch_bounds__(256) void k_offconv(const unsigned short* __restrict__ xbf,
                                                 const unsigned short* __restrict__ wrep,
                                                 const float* __restrict__ bias,
                                                 float* __restrict__ om) {
  __shared__ __align__(16) unsigned short As[64][32];
  __shared__ __align__(16) unsigned short Bs[32][32];
  int bm = blockIdx.x;              // 0..255
  int t = threadIdx.x;
  int wave = t >> 6, lane = t & 63;
  int n = bm >> 6, oy = bm & 63;
  f32x4 acc0 = {0.f, 0.f, 0.f, 0.f};
  f32x4 acc1 = {0.f, 0.f, 0.f, 0.f};
  int arow = t >> 2;                // 0..63 == ox
  int ak   = (t & 3) * 8;           // k-offset within 32 (elements)
  for (int kt = 0; kt < 72; ++kt) {
    int kk = kt >> 3;
    int c0 = (kt & 7) * 32;
    int dy = kk / 3 - 1, dx = kk % 3 - 1;
    int yy = oy + dy;
    int xxg = arow + dx;
    int4 av = {0, 0, 0, 0};
    if ((unsigned)yy < 64u && (unsigned)xxg < 64u)
      av = *(const int4*)(xbf + (size_t)(((n * 64 + yy) * 64 + xxg) * 256 + c0 + ak));
    int4 bv = {0, 0, 0, 0};
    if (t < 128) bv = *(const int4*)(wrep + (size_t)((t >> 2) * 2304 + kt * 32 + ak));
    __syncthreads();
    *(int4*)&As[arow][ak] = av;
    if (t < 128) *(int4*)&Bs[t >> 2][ak] = bv;
    __syncthreads();
    int mrow = lane & 15;
    int qk = (lane >> 4) * 8;
    bf16x8 a  = *(const bf16x8*)&As[wave * 16 + mrow][qk];
    bf16x8 b0 = *(const bf16x8*)&Bs[mrow][qk];
    bf16x8 b1 = *(const bf16x8*)&Bs[16 + mrow][qk];
    acc0 = __builtin_amdgcn_mfma_f32_16x16x32_bf16(a, b0, acc0, 0, 0, 0);
    acc1 = __builtin_amdgcn_mfma_f32_16x16x32_bf16(a, b1, acc1, 0, 0, 0);
  }
  int q = lane >> 4, cc = lane & 15;
  int r0 = bm * 64;
#pragma unroll
  for (int nt = 0; nt < 2; ++nt) {
    f32x4 a = nt ? acc1 : acc0;
    int oc = nt * 16 + cc;
    float bv = (oc < 27) ? bias[oc] : 0.f;
#pragma unroll
    for (int rg = 0; rg < 4; ++rg) {
      int p = r0 + wave * 16 + q * 4 + rg;
      float v = a[rg] + bv;
      if (oc >= 18 && oc < 27) v = 1.f / (1.f + __expf(-v));
      om[p * 32 + oc] = v;
    }
  }
}

// ---------------- bilinear sampling * mask -> col bf16 ----------------
__global__ __launch_bounds__(256) void k_sample(const unsigned short* __restrict__ xbf,
                                                const float* __restrict__ om,
                                                unsigned short* __restrict__ col) {
  int r = blockIdx.x;
  int c = threadIdx.x;
  int n = r >> 12, yx = r & 4095, oy = yx >> 6, ox = yx & 63;
  const float* omr = om + r * 32;
  const unsigned short* xb = xbf + (size_t)n * 4096 * 256;
  unsigned short* cr = col + (size_t)r * 2304;
#pragma unroll
  for (int kk = 0; kk < 9; ++kk) {
    int dy = kk / 3 - 1, dx = kk % 3 - 1;
    float offy = omr[2 * kk], offx = omr[2 * kk + 1], m = omr[18 + kk];
    float py  = (float)(oy + 1 + dy) + offy;
    float pxv = (float)(ox + 1 + dx) + offx;
    py  = fminf(fmaxf(py, 0.f), 65.f);
    pxv = fminf(fmaxf(pxv, 0.f), 65.f);
    float y1 = floorf(py), x1 = floorf(pxv);
    float ly = py - y1, lx = pxv - x1;
    float hy = 1.f - ly, hx = 1.f - lx;
    int iy = (int)y1, ix = (int)x1;
    // padded coords: valid (nonzero) iff 1<=coord<=64; x index = coord-1
    float v1 = 0.f, v2 = 0.f, v3 = 0.f, v4 = 0.f;
    bool yv0 = (iy >= 1 && iy <= 64);
    bool yv1 = (iy + 1 <= 64);           // iy+1 >= 1 always (iy >= 0)
    bool xv0 = (ix >= 1 && ix <= 64);
    bool xv1 = (ix + 1 <= 64);
    if (yv0 && xv0) v1 = bf2f(xb[(((iy - 1) << 6) + (ix - 1)) * 256 + c]);
    if (yv0 && xv1) v2 = bf2f(xb[(((iy - 1) << 6) + ix) * 256 + c]);
    if (yv1 && xv0) v3 = bf2f(xb[((iy << 6) + (ix - 1)) * 256 + c]);
    if (yv1 && xv1) v4 = bf2f(xb[((iy << 6) + ix) * 256 + c]);
    float val = hy * hx * v1 + hy * lx * v2 + ly * hx * v3 + ly * lx * v4;
    cr[kk * 256 + c] = f2bf(val * m);
  }
}

// ---------------- main GEMM: out[n][o][yx] = col[r][:] . wmain[o][:] ----------------
// BM=128, BN=64, BK=32; 4 waves in 2x2; each wave 64x32 (4x2 16x16 frags)
__global__ __launch_bounds__(256) void k_gemm(const unsigned short* __restrict__ col,
                                              const unsigned short* __restrict__ wB,
                                              float* __restrict__ out) {
  __shared__ __align__(16) unsigned short As[128][32];
  __shared__ __align__(16) unsigned short Bs[64][32];
  int bm = blockIdx.x;   // 0..127
  int bn = blockIdx.y;   // 0..3
  int t = threadIdx.x;
  int wave = t >> 6, lane = t & 63;
  int wm = wave & 1, wn = wave >> 1;
  int r0 = bm * 128, o0 = bn * 64;
  f32x4 acc[4][2];
#pragma unroll
  for (int mt = 0; mt < 4; ++mt)
#pragma unroll
    for (int nt = 0; nt < 2; ++nt) acc[mt][nt] = (f32x4){0.f, 0.f, 0.f, 0.f};
  int arow = t >> 2;            // 0..63 ; second chunk at +64
  int ak   = (t & 3) * 8;
  const unsigned short* Ab = col + (size_t)r0 * 2304;
  const unsigned short* Bb = wB + (size_t)o0 * 2304;
  for (int kt = 0; kt < 72; ++kt) {
    int kof = kt * 32 + ak;
    int4 a0 = *(const int4*)(Ab + (size_t)arow * 2304 + kof);
    int4 a1 = *(const int4*)(Ab + (size_t)(arow + 64) * 2304 + kof);
    int4 b0 = *(const int4*)(Bb + (size_t)arow * 2304 + kof);
    __syncthreads();
    *(int4*)&As[arow][ak] = a0;
    *(int4*)&As[arow + 64][ak] = a1;
    *(int4*)&Bs[arow][ak] = b0;
    __syncthreads();
    int mrow = lane & 15, qk = (lane >> 4) * 8;
    bf16x8 af[4], bfr[2];
#pragma unroll
    for (int mt = 0; mt < 4; ++mt) af[mt] = *(const bf16x8*)&As[wm * 64 + mt * 16 + mrow][qk];
#pragma unroll
    for (int nt = 0; nt < 2; ++nt) bfr[nt] = *(const bf16x8*)&Bs[wn * 32 + nt * 16 + mrow][qk];
#pragma unroll
    for (int mt = 0; mt < 4; ++mt)
#pragma unroll
      for (int nt = 0; nt < 2; ++nt)
        acc[mt][nt] = __builtin_amdgcn_mfma_f32_16x16x32_bf16(af[mt], bfr[nt], acc[mt][nt], 0, 0, 0);
  }
  int q = lane >> 4, cc = lane & 15;
#pragma unroll
  for (int mt = 0; mt < 4; ++mt)
#pragma unroll
    for (int nt = 0; nt < 2; ++nt) {
      int p = r0 + wm * 64 + mt * 16 + q * 4;
      int o = o0 + wn * 32 + nt * 16 + cc;
      int n = p >> 12, yx = p & 4095;
      *(f32x4*)(out + ((size_t)(n * 256 + o) << 12) + yx) = acc[mt][nt];
    }
}

extern "C" void kernel_launch(void* const* d_in, const int* in_sizes, int n_in,
                              void* d_out, int out_size, void* d_ws, size_t ws_size,
                              hipStream_t stream) {
  const float* x     = (const float*)d_in[0];
  const float* w_off = (const float*)d_in[1];
  const float* b_off = (const float*)d_in[2];
  const float* dcn_w = (const float*)d_in[3];
  float* out = (float*)d_out;
  char* ws = (char*)d_ws;
  unsigned short* xbf   = (unsigned short*)(ws + XBF_OFF);
  unsigned short* wrep  = (unsigned short*)(ws + WREP_OFF);
  unsigned short* wmain = (unsigned short*)(ws + WMAIN_OFF);
  float*          om    = (float*)(ws + OM_OFF);
  unsigned short* col   = (unsigned short*)(ws + COL_OFF);

  k_transpose<<<dim3(64, 8, 4), 256, 0, stream>>>(x, xbf);
  k_repack<<<288, 256, 0, stream>>>(w_off, wrep, 27, 32);
  k_repack<<<2304, 256, 0, stream>>>(dcn_w, wmain, 256, 256);
  k_offconv<<<256, 256, 0, stream>>>(xbf, wrep, b_off, om);
  k_sample<<<16384, 256, 0, stream>>>(xbf, om, col);
  k_gemm<<<dim3(128, 4), 256, 0, stream>>>(col, wmain, out);
}

// Round 2
// 177.443 us; speedup vs baseline: 1.3263x; 1.3263x over previous
//
#include <hip/hip_runtime.h>

// DCNv2 forward, MI355X (gfx950).
//  k_transpose: x NCHW f32 -> x_bf NHWC bf16
//  k_repack:    both weight tensors -> [oc][kk*256+c] bf16
//  k_offconv:   MFMA GEMM, implicit im2col -> om[r][32] f32 (bias+sigmoid applied)
//  k_sample:    bilinear gather * mask -> col[r][2304] bf16 (8 ch/thread, 16B vec)
//  k_gemm:      m97-style MFMA GEMM (128x128 tile, global_load_lds w16) -> out f32

typedef __bf16 bf16x8 __attribute__((ext_vector_type(8)));
typedef float  f32x4  __attribute__((ext_vector_type(4)));
typedef unsigned short ushort8 __attribute__((ext_vector_type(8)));

#define XBF_OFF   0u            // 4*4096*256*2  = 8,388,608
#define WREP_OFF  8388608u      // 32*2304*2     =   147,456
#define WMAIN_OFF 8536064u      // 256*2304*2    = 1,179,648
#define OM_OFF    9715712u      // 16384*32*4    = 2,097,152
#define COL_OFF   11812864u     // 16384*2304*2  = 75,497,472

__device__ __forceinline__ unsigned short f2bf(float f) {
  unsigned int u = __float_as_uint(f);
  u += 0x7fffu + ((u >> 16) & 1u);
  return (unsigned short)(u >> 16);
}
__device__ __forceinline__ float bf2f(unsigned short h) {
  return __uint_as_float(((unsigned int)h) << 16);
}

// ---------------- x NCHW -> NHWC bf16 ----------------
__global__ __launch_bounds__(256) void k_transpose(const float* __restrict__ x,
                                                   unsigned short* __restrict__ xbf) {
  __shared__ float tile[32][65];
  int n  = blockIdx.z;
  int cb = blockIdx.y;
  int xb = blockIdx.x;
  int t  = threadIdx.x;
  int xx  = t & 63;
  int cc0 = t >> 6;
#pragma unroll
  for (int j = 0; j < 8; ++j) {
    int cc = cc0 + j * 4;
    tile[cc][xx] = x[((size_t)(n * 256 + cb * 32 + cc) << 12) + xb * 64 + xx];
  }
  __syncthreads();
  int ccw = t & 31;
  int xw0 = t >> 5;
#pragma unroll
  for (int j = 0; j < 8; ++j) {
    int xw = xw0 + j * 8;
    xbf[((size_t)((n << 12) + xb * 64 + xw)) * 256 + cb * 32 + ccw] = f2bf(tile[ccw][xw]);
  }
}

// ---------------- weight repack (both tensors in one launch) ----------------
__global__ __launch_bounds__(256) void k_repack(const float* __restrict__ w_off,
                                                const float* __restrict__ dcn_w,
                                                unsigned short* __restrict__ wrep,
                                                unsigned short* __restrict__ wmain) {
  int idx = blockIdx.x * 256 + threadIdx.x;
  if (idx < 32 * 2304) {
    int oc  = idx / 2304;
    int rem = idx - oc * 2304;
    int kk  = rem >> 8;
    int c   = rem & 255;
    wrep[idx] = f2bf((oc < 27) ? w_off[oc * 2304 + c * 9 + kk] : 0.f);
  } else {
    int j = idx - 32 * 2304;
    int oc  = j / 2304;
    int rem = j - oc * 2304;
    int kk  = rem >> 8;
    int c   = rem & 255;
    wmain[j] = f2bf(dcn_w[oc * 2304 + c * 9 + kk]);
  }
}

// ---------------- offset-field conv ----------------
__global__ __launch_bounds__(256) void k_offconv(const unsigned short* __restrict__ xbf,
                                                 const unsigned short* __restrict__ wrep,
                                                 const float* __restrict__ bias,
                                                 float* __restrict__ om) {
  __shared__ __align__(16) unsigned short As[64][32];
  __shared__ __align__(16) unsigned short Bs[32][32];
  int bm = blockIdx.x;
  int t = threadIdx.x;
  int wave = t >> 6, lane = t & 63;
  int n = bm >> 6, oy = bm & 63;
  f32x4 acc0 = {0.f, 0.f, 0.f, 0.f};
  f32x4 acc1 = {0.f, 0.f, 0.f, 0.f};
  int arow = t >> 2;
  int ak   = (t & 3) * 8;
  for (int kt = 0; kt < 72; ++kt) {
    int kk = kt >> 3;
    int c0 = (kt & 7) * 32;
    int dy = kk / 3 - 1, dx = kk % 3 - 1;
    int yy = oy + dy;
    int xxg = arow + dx;
    int4 av = {0, 0, 0, 0};
    if ((unsigned)yy < 64u && (unsigned)xxg < 64u)
      av = *(const int4*)(xbf + (size_t)(((n * 64 + yy) * 64 + xxg) * 256 + c0 + ak));
    int4 bv = {0, 0, 0, 0};
    if (t < 128) bv = *(const int4*)(wrep + (size_t)((t >> 2) * 2304 + kt * 32 + ak));
    __syncthreads();
    *(int4*)&As[arow][ak] = av;
    if (t < 128) *(int4*)&Bs[t >> 2][ak] = bv;
    __syncthreads();
    int mrow = lane & 15;
    int qk = (lane >> 4) * 8;
    bf16x8 a  = *(const bf16x8*)&As[wave * 16 + mrow][qk];
    bf16x8 b0 = *(const bf16x8*)&Bs[mrow][qk];
    bf16x8 b1 = *(const bf16x8*)&Bs[16 + mrow][qk];
    acc0 = __builtin_amdgcn_mfma_f32_16x16x32_bf16(a, b0, acc0, 0, 0, 0);
    acc1 = __builtin_amdgcn_mfma_f32_16x16x32_bf16(a, b1, acc1, 0, 0, 0);
  }
  int q = lane >> 4, cc = lane & 15;
  int r0 = bm * 64;
#pragma unroll
  for (int nt = 0; nt < 2; ++nt) {
    f32x4 a = nt ? acc1 : acc0;
    int oc = nt * 16 + cc;
    float bv = (oc < 27) ? bias[oc] : 0.f;
#pragma unroll
    for (int rg = 0; rg < 4; ++rg) {
      int p = r0 + wave * 16 + q * 4 + rg;
      float v = a[rg] + bv;
      if (oc >= 18 && oc < 27) v = 1.f / (1.f + __expf(-v));
      om[p * 32 + oc] = v;
    }
  }
}

// ---------------- bilinear sampling * mask -> col bf16 (8 ch/thread) ----------------
__global__ __launch_bounds__(256) void k_sample(const unsigned short* __restrict__ xbf,
                                                const float* __restrict__ om,
                                                unsigned short* __restrict__ col) {
  int t = threadIdx.x;
  int g = t >> 5;        // row subgroup 0..7
  int c0 = (t & 31) * 8; // channel offset
  int r = blockIdx.x * 8 + g;
  int n = r >> 12, yx = r & 4095, oy = yx >> 6, ox = yx & 63;
  const float* omr = om + r * 32;
  const unsigned short* xb = xbf + (size_t)n * (4096 * 256);
  unsigned short* cr = col + (size_t)r * 2304;
#pragma unroll
  for (int kk = 0; kk < 9; ++kk) {
    float offy = omr[2 * kk], offx = omr[2 * kk + 1], m = omr[18 + kk];
    float py = (float)(oy + (kk / 3)) + offy;     // oy + 1 + (kk/3 - 1)
    float px = (float)(ox + (kk % 3)) + offx;
    py = fminf(fmaxf(py, 0.f), 65.f);
    px = fminf(fmaxf(px, 0.f), 65.f);
    float fy = floorf(py), fx = floorf(px);
    float ly = py - fy, lx = px - fx;
    float hy = 1.f - ly, hx = 1.f - lx;
    int iy = (int)fy, ix = (int)fx;               // 0..65 (padded coords)
    bool yv0 = (iy >= 1) && (iy <= 64);
    bool yv1 = (iy <= 63);
    bool xv0 = (ix >= 1) && (ix <= 64);
    bool xv1 = (ix <= 63);
    int y0 = min(max(iy - 1, 0), 63);
    int y1 = min(iy, 63);
    int x0 = min(max(ix - 1, 0), 63);
    int x1 = min(ix, 63);
    float w1 = (yv0 && xv0) ? hy * hx * m : 0.f;
    float w2 = (yv0 && xv1) ? hy * lx * m : 0.f;
    float w3 = (yv1 && xv0) ? ly * hx * m : 0.f;
    float w4 = (yv1 && xv1) ? ly * lx * m : 0.f;
    ushort8 a  = *(const ushort8*)(xb + (((y0 << 6) + x0) * 256 + c0));
    ushort8 b  = *(const ushort8*)(xb + (((y0 << 6) + x1) * 256 + c0));
    ushort8 cv = *(const ushort8*)(xb + (((y1 << 6) + x0) * 256 + c0));
    ushort8 d  = *(const ushort8*)(xb + (((y1 << 6) + x1) * 256 + c0));
    ushort8 res;
#pragma unroll
    for (int j = 0; j < 8; ++j) {
      float v = w1 * bf2f(a[j]) + w2 * bf2f(b[j]) + w3 * bf2f(cv[j]) + w4 * bf2f(d[j]);
      res[j] = f2bf(v);
    }
    *(ushort8*)(cr + kk * 256 + c0) = res;
  }
}

// ---------------- main GEMM: m97-style 128x128 tile, BK=64, global_load_lds ----------------
__global__ __launch_bounds__(256) void k_gemm(const unsigned short* __restrict__ col,
                                              const unsigned short* __restrict__ wB,
                                              float* __restrict__ out) {
  __shared__ __align__(16) unsigned short As[128 * 64];
  __shared__ __align__(16) unsigned short Bs[128 * 64];
  int t = threadIdx.x;
  int wave = t >> 6, lane = t & 63;
  int wm = wave & 1, wn = wave >> 1;
  int r0 = blockIdx.x * 128, o0 = blockIdx.y * 128;
  f32x4 acc[4][4];
#pragma unroll
  for (int mt = 0; mt < 4; ++mt)
#pragma unroll
    for (int nt = 0; nt < 4; ++nt) acc[mt][nt] = (f32x4){0.f, 0.f, 0.f, 0.f};

  // staging: wave w covers rows w*32..w*32+31; chunk j covers rows +j*8;
  // lane i -> row + (i>>3), elem (i&7)*8. LDS dest = wave-uniform base + lane*16B.
  int srow = wave * 32 + (lane >> 3);
  int selem = (lane & 7) * 8;
  const unsigned short* Ag = col + (size_t)(r0 + srow) * 2304 + selem;
  const unsigned short* Bg = wB  + (size_t)(o0 + srow) * 2304 + selem;

  for (int kt = 0; kt < 36; ++kt) {
    int kof = kt * 64;
    __syncthreads();
#pragma unroll
    for (int j = 0; j < 4; ++j) {
      __builtin_amdgcn_global_load_lds(
          (const __attribute__((address_space(1))) unsigned int*)(Ag + (size_t)j * 8 * 2304 + kof),
          (__attribute__((address_space(3))) unsigned int*)(As + wave * 2048 + j * 512),
          16, 0, 0);
      __builtin_amdgcn_global_load_lds(
          (const __attribute__((address_space(1))) unsigned int*)(Bg + (size_t)j * 8 * 2304 + kof),
          (__attribute__((address_space(3))) unsigned int*)(Bs + wave * 2048 + j * 512),
          16, 0, 0);
    }
    __syncthreads();
    int mr = lane & 15;
#pragma unroll
    for (int kh = 0; kh < 2; ++kh) {
      int qk = (lane >> 4) * 8 + kh * 32;
      bf16x8 af[4], bfv[4];
#pragma unroll
      for (int mt = 0; mt < 4; ++mt)
        af[mt] = *(const bf16x8*)(As + (wm * 64 + mt * 16 + mr) * 64 + qk);
#pragma unroll
      for (int nt = 0; nt < 4; ++nt)
        bfv[nt] = *(const bf16x8*)(Bs + (wn * 64 + nt * 16 + mr) * 64 + qk);
#pragma unroll
      for (int mt = 0; mt < 4; ++mt)
#pragma unroll
        for (int nt = 0; nt < 4; ++nt)
          acc[mt][nt] = __builtin_amdgcn_mfma_f32_16x16x32_bf16(af[mt], bfv[nt], acc[mt][nt], 0, 0, 0);
    }
  }
  int q = lane >> 4, cc = lane & 15;
#pragma unroll
  for (int mt = 0; mt < 4; ++mt)
#pragma unroll
    for (int nt = 0; nt < 4; ++nt) {
      int p = r0 + wm * 64 + mt * 16 + q * 4;
      int o = o0 + wn * 64 + nt * 16 + cc;
      int n = p >> 12, yx = p & 4095;
      *(f32x4*)(out + ((size_t)(n * 256 + o) << 12) + yx) = acc[mt][nt];
    }
}

extern "C" void kernel_launch(void* const* d_in, const int* in_sizes, int n_in,
                              void* d_out, int out_size, void* d_ws, size_t ws_size,
                              hipStream_t stream) {
  const float* x     = (const float*)d_in[0];
  const float* w_off = (const float*)d_in[1];
  const float* b_off = (const float*)d_in[2];
  const float* dcn_w = (const float*)d_in[3];
  float* out = (float*)d_out;
  char* ws = (char*)d_ws;
  unsigned short* xbf   = (unsigned short*)(ws + XBF_OFF);
  unsigned short* wrep  = (unsigned short*)(ws + WREP_OFF);
  unsigned short* wmain = (unsigned short*)(ws + WMAIN_OFF);
  float*          om    = (float*)(ws + OM_OFF);
  unsigned short* col   = (unsigned short*)(ws + COL_OFF);

  k_transpose<<<dim3(64, 8, 4), 256, 0, stream>>>(x, xbf);
  k_repack<<<(288 * 2304) / 256, 256, 0, stream>>>(w_off, dcn_w, wrep, wmain);
  k_offconv<<<256, 256, 0, stream>>>(xbf, wrep, b_off, om);
  k_sample<<<2048, 256, 0, stream>>>(xbf, om, col);
  k_gemm<<<dim3(128, 2), 256, 0, stream>>>(col, wmain, out);
}

// Round 3
// 172.745 us; speedup vs baseline: 1.3624x; 1.0272x over previous
//
#include <hip/hip_runtime.h>

// DCNv2 forward, MI355X (gfx950).
//  k_transpose: x NCHW f32 -> x_bf NHWC bf16
//  k_repack:    both weight tensors -> [oc][kk*256+c] bf16
//  k_offconv:   MFMA GEMM, implicit im2col -> om[r][32] f32 (bias+sigmoid applied)
//  k_sample:    bilinear gather * mask -> col[r][2304] bf16 (8 ch/thread, 16B vec)
//  k_gemm:      128x128 MFMA GEMM, global_load_lds w16, XOR-swizzled LDS (bank-
//               conflict-free), explicit double buffer (grid=256 -> 1 block/CU,
//               so dbuf is the only latency overlap available)

typedef __bf16 bf16x8 __attribute__((ext_vector_type(8)));
typedef float  f32x4  __attribute__((ext_vector_type(4)));
typedef unsigned short ushort8 __attribute__((ext_vector_type(8)));

#define XBF_OFF   0u            // 4*4096*256*2  = 8,388,608
#define WREP_OFF  8388608u      // 32*2304*2     =   147,456
#define WMAIN_OFF 8536064u      // 256*2304*2    = 1,179,648
#define OM_OFF    9715712u      // 16384*32*4    = 2,097,152
#define COL_OFF   11812864u     // 16384*2304*2  = 75,497,472

__device__ __forceinline__ unsigned short f2bf(float f) {
  unsigned int u = __float_as_uint(f);
  u += 0x7fffu + ((u >> 16) & 1u);
  return (unsigned short)(u >> 16);
}
__device__ __forceinline__ float bf2f(unsigned short h) {
  return __uint_as_float(((unsigned int)h) << 16);
}

// ---------------- x NCHW -> NHWC bf16 ----------------
__global__ __launch_bounds__(256) void k_transpose(const float* __restrict__ x,
                                                   unsigned short* __restrict__ xbf) {
  __shared__ float tile[32][65];
  int n  = blockIdx.z;
  int cb = blockIdx.y;
  int xb = blockIdx.x;
  int t  = threadIdx.x;
  int xx  = t & 63;
  int cc0 = t >> 6;
#pragma unroll
  for (int j = 0; j < 8; ++j) {
    int cc = cc0 + j * 4;
    tile[cc][xx] = x[((size_t)(n * 256 + cb * 32 + cc) << 12) + xb * 64 + xx];
  }
  __syncthreads();
  int ccw = t & 31;
  int xw0 = t >> 5;
#pragma unroll
  for (int j = 0; j < 8; ++j) {
    int xw = xw0 + j * 8;
    xbf[((size_t)((n << 12) + xb * 64 + xw)) * 256 + cb * 32 + ccw] = f2bf(tile[ccw][xw]);
  }
}

// ---------------- weight repack (both tensors in one launch) ----------------
__global__ __launch_bounds__(256) void k_repack(const float* __restrict__ w_off,
                                                const float* __restrict__ dcn_w,
                                                unsigned short* __restrict__ wrep,
                                                unsigned short* __restrict__ wmain) {
  int idx = blockIdx.x * 256 + threadIdx.x;
  if (idx < 32 * 2304) {
    int oc  = idx / 2304;
    int rem = idx - oc * 2304;
    int kk  = rem >> 8;
    int c   = rem & 255;
    wrep[idx] = f2bf((oc < 27) ? w_off[oc * 2304 + c * 9 + kk] : 0.f);
  } else {
    int j = idx - 32 * 2304;
    int oc  = j / 2304;
    int rem = j - oc * 2304;
    int kk  = rem >> 8;
    int c   = rem & 255;
    wmain[j] = f2bf(dcn_w[oc * 2304 + c * 9 + kk]);
  }
}

// ---------------- offset-field conv (LDS rows padded to 40: conflict-free) ----
__global__ __launch_bounds__(256) void k_offconv(const unsigned short* __restrict__ xbf,
                                                 const unsigned short* __restrict__ wrep,
                                                 const float* __restrict__ bias,
                                                 float* __restrict__ om) {
  __shared__ __align__(16) unsigned short As[64][40];
  __shared__ __align__(16) unsigned short Bs[32][40];
  int bm = blockIdx.x;
  int t = threadIdx.x;
  int wave = t >> 6, lane = t & 63;
  int n = bm >> 6, oy = bm & 63;
  f32x4 acc0 = {0.f, 0.f, 0.f, 0.f};
  f32x4 acc1 = {0.f, 0.f, 0.f, 0.f};
  int arow = t >> 2;
  int ak   = (t & 3) * 8;
  for (int kt = 0; kt < 72; ++kt) {
    int kk = kt >> 3;
    int c0 = (kt & 7) * 32;
    int dy = kk / 3 - 1, dx = kk % 3 - 1;
    int yy = oy + dy;
    int xxg = arow + dx;
    int4 av = {0, 0, 0, 0};
    if ((unsigned)yy < 64u && (unsigned)xxg < 64u)
      av = *(const int4*)(xbf + (size_t)(((n * 64 + yy) * 64 + xxg) * 256 + c0 + ak));
    int4 bv = {0, 0, 0, 0};
    if (t < 128) bv = *(const int4*)(wrep + (size_t)((t >> 2) * 2304 + kt * 32 + ak));
    __syncthreads();
    *(int4*)&As[arow][ak] = av;
    if (t < 128) *(int4*)&Bs[t >> 2][ak] = bv;
    __syncthreads();
    int mrow = lane & 15;
    int qk = (lane >> 4) * 8;
    bf16x8 a  = *(const bf16x8*)&As[wave * 16 + mrow][qk];
    bf16x8 b0 = *(const bf16x8*)&Bs[mrow][qk];
    bf16x8 b1 = *(const bf16x8*)&Bs[16 + mrow][qk];
    acc0 = __builtin_amdgcn_mfma_f32_16x16x32_bf16(a, b0, acc0, 0, 0, 0);
    acc1 = __builtin_amdgcn_mfma_f32_16x16x32_bf16(a, b1, acc1, 0, 0, 0);
  }
  int q = lane >> 4, cc = lane & 15;
  int r0 = bm * 64;
#pragma unroll
  for (int nt = 0; nt < 2; ++nt) {
    f32x4 a = nt ? acc1 : acc0;
    int oc = nt * 16 + cc;
    float bv = (oc < 27) ? bias[oc] : 0.f;
#pragma unroll
    for (int rg = 0; rg < 4; ++rg) {
      int p = r0 + wave * 16 + q * 4 + rg;
      float v = a[rg] + bv;
      if (oc >= 18 && oc < 27) v = 1.f / (1.f + __expf(-v));
      om[p * 32 + oc] = v;
    }
  }
}

// ---------------- bilinear sampling * mask -> col bf16 (8 ch/thread) ----------------
__global__ __launch_bounds__(256) void k_sample(const unsigned short* __restrict__ xbf,
                                                const float* __restrict__ om,
                                                unsigned short* __restrict__ col) {
  int t = threadIdx.x;
  int g = t >> 5;
  int c0 = (t & 31) * 8;
  int r = blockIdx.x * 8 + g;
  int n = r >> 12, yx = r & 4095, oy = yx >> 6, ox = yx & 63;
  const float* omr = om + r * 32;
  const unsigned short* xb = xbf + (size_t)n * (4096 * 256);
  unsigned short* cr = col + (size_t)r * 2304;
#pragma unroll
  for (int kk = 0; kk < 9; ++kk) {
    float offy = omr[2 * kk], offx = omr[2 * kk + 1], m = omr[18 + kk];
    float py = (float)(oy + (kk / 3)) + offy;
    float px = (float)(ox + (kk % 3)) + offx;
    py = fminf(fmaxf(py, 0.f), 65.f);
    px = fminf(fmaxf(px, 0.f), 65.f);
    float fy = floorf(py), fx = floorf(px);
    float ly = py - fy, lx = px - fx;
    float hy = 1.f - ly, hx = 1.f - lx;
    int iy = (int)fy, ix = (int)fx;
    bool yv0 = (iy >= 1) && (iy <= 64);
    bool yv1 = (iy <= 63);
    bool xv0 = (ix >= 1) && (ix <= 64);
    bool xv1 = (ix <= 63);
    int y0 = min(max(iy - 1, 0), 63);
    int y1 = min(iy, 63);
    int x0 = min(max(ix - 1, 0), 63);
    int x1 = min(ix, 63);
    float w1 = (yv0 && xv0) ? hy * hx * m : 0.f;
    float w2 = (yv0 && xv1) ? hy * lx * m : 0.f;
    float w3 = (yv1 && xv0) ? ly * hx * m : 0.f;
    float w4 = (yv1 && xv1) ? ly * lx * m : 0.f;
    ushort8 a  = *(const ushort8*)(xb + (((y0 << 6) + x0) * 256 + c0));
    ushort8 b  = *(const ushort8*)(xb + (((y0 << 6) + x1) * 256 + c0));
    ushort8 cv = *(const ushort8*)(xb + (((y1 << 6) + x0) * 256 + c0));
    ushort8 d  = *(const ushort8*)(xb + (((y1 << 6) + x1) * 256 + c0));
    ushort8 res;
#pragma unroll
    for (int j = 0; j < 8; ++j) {
      float v = w1 * bf2f(a[j]) + w2 * bf2f(b[j]) + w3 * bf2f(cv[j]) + w4 * bf2f(d[j]);
      res[j] = f2bf(v);
    }
    *(ushort8*)(cr + kk * 256 + c0) = res;
  }
}

// ---------------- main GEMM: 128x128, XOR-swizzled LDS, double-buffered ------
// Swizzle: row r's 16B chunk c lives at LDS chunk (c ^ (r&7)) within r's 128B row.
// global_load_lds lane i loads global chunk ((i&7)^((i>>3)&7)) of row (i>>3), so
// the linear wave-uniform+lane*16B LDS write lands data in swizzled form.
__global__ __launch_bounds__(256) void k_gemm(const unsigned short* __restrict__ col,
                                              const unsigned short* __restrict__ wB,
                                              float* __restrict__ out) {
  __shared__ __align__(16) unsigned short As[2][128 * 64];
  __shared__ __align__(16) unsigned short Bs[2][128 * 64];
  int t = threadIdx.x;
  int wave = t >> 6, lane = t & 63;
  int wm = wave & 1, wn = wave >> 1;
  int r0 = blockIdx.x * 128, o0 = blockIdx.y * 128;
  f32x4 acc[4][4];
#pragma unroll
  for (int mt = 0; mt < 4; ++mt)
#pragma unroll
    for (int nt = 0; nt < 4; ++nt) acc[mt][nt] = (f32x4){0.f, 0.f, 0.f, 0.f};

  int srow8 = lane >> 3;                       // 0..7
  int swz   = ((lane & 7) ^ srow8) * 8;        // swizzled element offset in row
  const unsigned short* Ag = col + (size_t)(r0 + wave * 32 + srow8) * 2304 + swz;
  const unsigned short* Bg = wB  + (size_t)(o0 + wave * 32 + srow8) * 2304 + swz;

#define STAGE(buf, kt)                                                                 \
  {                                                                                    \
    int kof = (kt) * 64;                                                               \
    _Pragma("unroll")                                                                  \
    for (int j = 0; j < 4; ++j) {                                                      \
      __builtin_amdgcn_global_load_lds(                                                \
          (const __attribute__((address_space(1))) unsigned int*)(Ag + (size_t)(j * 8) * 2304 + kof), \
          (__attribute__((address_space(3))) unsigned int*)(As[buf] + wave * 2048 + j * 512),         \
          16, 0, 0);                                                                   \
      __builtin_amdgcn_global_load_lds(                                                \
          (const __attribute__((address_space(1))) unsigned int*)(Bg + (size_t)(j * 8) * 2304 + kof), \
          (__attribute__((address_space(3))) unsigned int*)(Bs[buf] + wave * 2048 + j * 512),         \
          16, 0, 0);                                                                   \
    }                                                                                  \
  }

  STAGE(0, 0);
  int mr = lane & 15;
  int q  = lane >> 4;
  int xr = mr & 7;                              // read-side swizzle key
  for (int kt = 0; kt < 36; ++kt) {
    int cur = kt & 1;
    __syncthreads();                            // drains buf[cur] loads (issued one compute-phase ago)
    if (kt + 1 < 36) STAGE(cur ^ 1, kt + 1);
#pragma unroll
    for (int kh = 0; kh < 2; ++kh) {
      int cbase = q + kh * 4;
      int coff = (cbase ^ xr) * 8;
      bf16x8 af[4], bfv[4];
#pragma unroll
      for (int mt = 0; mt < 4; ++mt)
        af[mt] = *(const bf16x8*)(As[cur] + (wm * 64 + mt * 16 + mr) * 64 + coff);
#pragma unroll
      for (int nt = 0; nt < 4; ++nt)
        bfv[nt] = *(const bf16x8*)(Bs[cur] + (wn * 64 + nt * 16 + mr) * 64 + coff);
#pragma unroll
      for (int mt = 0; mt < 4; ++mt)
#pragma unroll
        for (int nt = 0; nt < 4; ++nt)
          acc[mt][nt] = __builtin_amdgcn_mfma_f32_16x16x32_bf16(af[mt], bfv[nt], acc[mt][nt], 0, 0, 0);
    }
  }
#undef STAGE
  int cc = mr;
#pragma unroll
  for (int mt = 0; mt < 4; ++mt)
#pragma unroll
    for (int nt = 0; nt < 4; ++nt) {
      int p = r0 + wm * 64 + mt * 16 + q * 4;
      int o = o0 + wn * 64 + nt * 16 + cc;
      int n = p >> 12, yx = p & 4095;
      *(f32x4*)(out + ((size_t)(n * 256 + o) << 12) + yx) = acc[mt][nt];
    }
}

extern "C" void kernel_launch(void* const* d_in, const int* in_sizes, int n_in,
                              void* d_out, int out_size, void* d_ws, size_t ws_size,
                              hipStream_t stream) {
  const float* x     = (const float*)d_in[0];
  const float* w_off = (const float*)d_in[1];
  const float* b_off = (const float*)d_in[2];
  const float* dcn_w = (const float*)d_in[3];
  float* out = (float*)d_out;
  char* ws = (char*)d_ws;
  unsigned short* xbf   = (unsigned short*)(ws + XBF_OFF);
  unsigned short* wrep  = (unsigned short*)(ws + WREP_OFF);
  unsigned short* wmain = (unsigned short*)(ws + WMAIN_OFF);
  float*          om    = (float*)(ws + OM_OFF);
  unsigned short* col   = (unsigned short*)(ws + COL_OFF);

  k_transpose<<<dim3(64, 8, 4), 256, 0, stream>>>(x, xbf);
  k_repack<<<(288 * 2304) / 256, 256, 0, stream>>>(w_off, dcn_w, wrep, wmain);
  k_offconv<<<256, 256, 0, stream>>>(xbf, wrep, b_off, om);
  k_sample<<<2048, 256, 0, stream>>>(xbf, om, col);
  k_gemm<<<dim3(128, 2), 256, 0, stream>>>(col, wmain, out);
}

// Round 4
// 167.157 us; speedup vs baseline: 1.4080x; 1.0334x over previous
//
#include <hip/hip_runtime.h>

// DCNv2 forward, MI355X (gfx950).
//  k_transpose:  x NCHW f32 -> x_bf NHWC bf16
//  k_repack:     both weight tensors -> [oc][kk*256+c] bf16
//  k_offconv:    MFMA GEMM, implicit im2col -> om[r][32] f32 (bias+sigmoid), reg-prefetch
//  k_gemm_fused: deformable-im2col fused GEMM: A-tile built in LDS by in-register
//                bilinear sampling from xbf (no col intermediate), B staged via
//                global_load_lds w16 + XOR swizzle, both double-buffered.
//                512 thr (8 waves = 2/SIMD) for latency overlap at 1 block/CU.

typedef __bf16 bf16x8 __attribute__((ext_vector_type(8)));
typedef float  f32x4  __attribute__((ext_vector_type(4)));
typedef unsigned short ushort8 __attribute__((ext_vector_type(8)));

#define XBF_OFF   0u            // 4*4096*256*2  = 8,388,608
#define WREP_OFF  8388608u      // 32*2304*2     =   147,456
#define WMAIN_OFF 8536064u      // 256*2304*2    = 1,179,648
#define OM_OFF    9715712u      // 16384*32*4    = 2,097,152

__device__ __forceinline__ unsigned short f2bf(float f) {
  unsigned int u = __float_as_uint(f);
  u += 0x7fffu + ((u >> 16) & 1u);
  return (unsigned short)(u >> 16);
}
__device__ __forceinline__ float bf2f(unsigned short h) {
  return __uint_as_float(((unsigned int)h) << 16);
}

// ---------------- x NCHW -> NHWC bf16 ----------------
__global__ __launch_bounds__(256) void k_transpose(const float* __restrict__ x,
                                                   unsigned short* __restrict__ xbf) {
  __shared__ float tile[32][65];
  int n  = blockIdx.z;
  int cb = blockIdx.y;
  int xb = blockIdx.x;
  int t  = threadIdx.x;
  int xx  = t & 63;
  int cc0 = t >> 6;
#pragma unroll
  for (int j = 0; j < 8; ++j) {
    int cc = cc0 + j * 4;
    tile[cc][xx] = x[((size_t)(n * 256 + cb * 32 + cc) << 12) + xb * 64 + xx];
  }
  __syncthreads();
  int ccw = t & 31;
  int xw0 = t >> 5;
#pragma unroll
  for (int j = 0; j < 8; ++j) {
    int xw = xw0 + j * 8;
    xbf[((size_t)((n << 12) + xb * 64 + xw)) * 256 + cb * 32 + ccw] = f2bf(tile[ccw][xw]);
  }
}

// ---------------- weight repack ----------------
__global__ __launch_bounds__(256) void k_repack(const float* __restrict__ w_off,
                                                const float* __restrict__ dcn_w,
                                                unsigned short* __restrict__ wrep,
                                                unsigned short* __restrict__ wmain) {
  int idx = blockIdx.x * 256 + threadIdx.x;
  if (idx < 32 * 2304) {
    int oc  = idx / 2304;
    int rem = idx - oc * 2304;
    int kk  = rem >> 8;
    int c   = rem & 255;
    wrep[idx] = f2bf((oc < 27) ? w_off[oc * 2304 + c * 9 + kk] : 0.f);
  } else {
    int j = idx - 32 * 2304;
    int oc  = j / 2304;
    int rem = j - oc * 2304;
    int kk  = rem >> 8;
    int c   = rem & 255;
    wmain[j] = f2bf(dcn_w[oc * 2304 + c * 9 + kk]);
  }
}

// ---------------- offset-field conv (depth-1 register prefetch) ----------------
__global__ __launch_bounds__(256) void k_offconv(const unsigned short* __restrict__ xbf,
                                                 const unsigned short* __restrict__ wrep,
                                                 const float* __restrict__ bias,
                                                 float* __restrict__ om) {
  __shared__ __align__(16) unsigned short As[64][40];
  __shared__ __align__(16) unsigned short Bs[32][40];
  int bm = blockIdx.x;
  int t = threadIdx.x;
  int wave = t >> 6, lane = t & 63;
  int n = bm >> 6, oy = bm & 63;
  f32x4 acc0 = {0.f, 0.f, 0.f, 0.f};
  f32x4 acc1 = {0.f, 0.f, 0.f, 0.f};
  int arow = t >> 2;
  int ak   = (t & 3) * 8;

  auto loadA = [&](int kt) {
    int kk = kt >> 3;
    int c0 = (kt & 7) * 32;
    int dy = kk / 3 - 1, dx = kk % 3 - 1;
    int yy = oy + dy;
    int xxg = arow + dx;
    int4 av = {0, 0, 0, 0};
    if ((unsigned)yy < 64u && (unsigned)xxg < 64u)
      av = *(const int4*)(xbf + (size_t)(((n * 64 + yy) * 64 + xxg) * 256 + c0 + ak));
    return av;
  };
  auto loadB = [&](int kt) {
    int4 bv = {0, 0, 0, 0};
    if (t < 128) bv = *(const int4*)(wrep + (size_t)((t >> 2) * 2304 + kt * 32 + ak));
    return bv;
  };

  int4 av = loadA(0), bv = loadB(0);
  for (int kt = 0; kt < 72; ++kt) {
    __syncthreads();
    *(int4*)&As[arow][ak] = av;
    if (t < 128) *(int4*)&Bs[t >> 2][ak] = bv;
    __syncthreads();
    if (kt < 71) { av = loadA(kt + 1); bv = loadB(kt + 1); }
    int mrow = lane & 15;
    int qk = (lane >> 4) * 8;
    bf16x8 a  = *(const bf16x8*)&As[wave * 16 + mrow][qk];
    bf16x8 b0 = *(const bf16x8*)&Bs[mrow][qk];
    bf16x8 b1 = *(const bf16x8*)&Bs[16 + mrow][qk];
    acc0 = __builtin_amdgcn_mfma_f32_16x16x32_bf16(a, b0, acc0, 0, 0, 0);
    acc1 = __builtin_amdgcn_mfma_f32_16x16x32_bf16(a, b1, acc1, 0, 0, 0);
  }
  int q = lane >> 4, cc = lane & 15;
  int r0 = bm * 64;
#pragma unroll
  for (int nt = 0; nt < 2; ++nt) {
    f32x4 a = nt ? acc1 : acc0;
    int oc = nt * 16 + cc;
    float bvl = (oc < 27) ? bias[oc] : 0.f;
#pragma unroll
    for (int rg = 0; rg < 4; ++rg) {
      int p = r0 + wave * 16 + q * 4 + rg;
      float v = a[rg] + bvl;
      if (oc >= 18 && oc < 27) v = 1.f / (1.f + __expf(-v));
      om[p * 32 + oc] = v;
    }
  }
}

// ---------------- fused deformable-im2col GEMM ----------------
// Grid (128, 2), 512 threads (8 waves, wm=wave&1 over M128, wn=wave>>1 over N128).
// K = 2304 = 9 kk * 256 c; kstep BK=64 (one kk, quarter of channels).
// A[row][c] sampled in-register (gathers prefetched one kstep ahead), ds_written
// XOR-swizzled. B staged global_load_lds w16, XOR-swizzled. Both double-buffered.
__global__ __launch_bounds__(512, 2) void k_gemm_fused(const unsigned short* __restrict__ xbf,
                                                       const float* __restrict__ om,
                                                       const unsigned short* __restrict__ wB,
                                                       float* __restrict__ out) {
  __shared__ __align__(16) unsigned short As[2][128 * 64];
  __shared__ __align__(16) unsigned short Bs[2][128 * 64];
  int t = threadIdx.x;
  int wave = t >> 6, lane = t & 63;
  int wm = wave & 1, wn = wave >> 1;            // wn 0..3
  int r0 = blockIdx.x * 128, o0 = blockIdx.y * 128;

  // --- sampling role: thread -> (row 0..127, 16 channels) ---
  int srow = t >> 2;
  int scol = (t & 3) * 16;
  int r = r0 + srow;
  int n = r >> 12, yx = r & 4095, oy = yx >> 6, ox = yx & 63;
  const unsigned short* xb = xbf + (size_t)n * (4096 * 256);
  const float* omr = om + (size_t)r * 32;
  int swrbase = srow * 64;                      // LDS row base for A writes
  int swr7 = srow & 7;

  // --- B staging role ---
  int brow = wave * 16 + (lane >> 3);
  int bswz = ((lane & 7) ^ ((lane >> 3) & 7)) * 8;
  const unsigned short* Bg = wB + (size_t)(o0 + brow) * 2304 + bswz;

  f32x4 acc[4][2];
#pragma unroll
  for (int mt = 0; mt < 4; ++mt)
#pragma unroll
    for (int nt = 0; nt < 2; ++nt) acc[mt][nt] = (f32x4){0.f, 0.f, 0.f, 0.f};

  float w1, w2, w3, w4;
  int a1, a2, a3, a4;                           // element offsets into xb
  auto params = [&](int kk) {
    float offy = omr[2 * kk], offx = omr[2 * kk + 1], m = omr[18 + kk];
    float py = (float)(oy + kk / 3) + offy;     // == oy+1 + (ky-1)
    float px = (float)(ox + kk % 3) + offx;
    py = fminf(fmaxf(py, 0.f), 65.f);
    px = fminf(fmaxf(px, 0.f), 65.f);
    float fy = floorf(py), fx = floorf(px);
    float ly = py - fy, lx = px - fx;
    float hy = 1.f - ly, hx = 1.f - lx;
    int iy = (int)fy, ix = (int)fx;
    bool yv0 = (iy >= 1) && (iy <= 64);
    bool yv1 = (iy <= 63);
    bool xv0 = (ix >= 1) && (ix <= 64);
    bool xv1 = (ix <= 63);
    int y0 = min(max(iy - 1, 0), 63);
    int y1 = min(iy, 63);
    int x0 = min(max(ix - 1, 0), 63);
    int x1 = min(ix, 63);
    w1 = (yv0 && xv0) ? hy * hx * m : 0.f;
    w2 = (yv0 && xv1) ? hy * lx * m : 0.f;
    w3 = (yv1 && xv0) ? ly * hx * m : 0.f;
    w4 = (yv1 && xv1) ? ly * lx * m : 0.f;
    a1 = ((y0 << 6) + x0) * 256;
    a2 = ((y0 << 6) + x1) * 256;
    a3 = ((y1 << 6) + x0) * 256;
    a4 = ((y1 << 6) + x1) * 256;
  };

  ushort8 g1[2], g2[2], g3[2], g4[2];
  auto gather = [&](int c0) {
#pragma unroll
    for (int g = 0; g < 2; ++g) {
      int c = c0 + scol + g * 8;
      g1[g] = *(const ushort8*)(xb + a1 + c);
      g2[g] = *(const ushort8*)(xb + a2 + c);
      g3[g] = *(const ushort8*)(xb + a3 + c);
      g4[g] = *(const ushort8*)(xb + a4 + c);
    }
  };
  auto blend_write = [&](int buf) {
#pragma unroll
    for (int g = 0; g < 2; ++g) {
      ushort8 res;
#pragma unroll
      for (int j = 0; j < 8; ++j) {
        float v = w1 * bf2f(g1[g][j]) + w2 * bf2f(g2[g][j]) +
                  w3 * bf2f(g3[g][j]) + w4 * bf2f(g4[g][j]);
        res[j] = f2bf(v);
      }
      int chunk = (t & 3) * 2 + g;
      *(ushort8*)&As[buf][swrbase + ((chunk ^ swr7) * 8)] = res;
    }
  };
  auto stageB = [&](int buf, int kt) {
    int kof = kt * 64;
#pragma unroll
    for (int j = 0; j < 2; ++j) {
      __builtin_amdgcn_global_load_lds(
          (const __attribute__((address_space(1))) unsigned int*)(Bg + (size_t)(j * 8) * 2304 + kof),
          (__attribute__((address_space(3))) unsigned int*)(&Bs[buf][(wave * 16 + j * 8) * 64] + lane * 8),
          16, 0, 0);
    }
  };

  // prologue: produce buffers 0 for kt=0
  params(0);
  gather(0);
  stageB(0, 0);
  blend_write(0);

  int mr = lane & 15, q = lane >> 4, xr = mr & 7;
  for (int kt = 0; kt < 36; ++kt) {
    int cur = kt & 1;
    __syncthreads();                 // A[cur] ds_writes visible; B[cur] loads drained
    if (kt < 35) {
      stageB(cur ^ 1, kt + 1);
      if (((kt + 1) & 3) == 0) params((kt + 1) >> 2);
      gather(((kt + 1) & 3) * 64);   // in flight during MFMA phase
    }
#pragma unroll
    for (int kh = 0; kh < 2; ++kh) {
      int coff = ((q + kh * 4) ^ xr) * 8;
      bf16x8 af[4], bfv[2];
#pragma unroll
      for (int mt = 0; mt < 4; ++mt)
        af[mt] = *(const bf16x8*)&As[cur][(wm * 64 + mt * 16 + mr) * 64 + coff];
#pragma unroll
      for (int nt = 0; nt < 2; ++nt)
        bfv[nt] = *(const bf16x8*)&Bs[cur][(wn * 32 + nt * 16 + mr) * 64 + coff];
#pragma unroll
      for (int mt = 0; mt < 4; ++mt)
#pragma unroll
        for (int nt = 0; nt < 2; ++nt)
          acc[mt][nt] = __builtin_amdgcn_mfma_f32_16x16x32_bf16(af[mt], bfv[nt], acc[mt][nt], 0, 0, 0);
    }
    if (kt < 35) blend_write(cur ^ 1);
  }

#pragma unroll
  for (int mt = 0; mt < 4; ++mt)
#pragma unroll
    for (int nt = 0; nt < 2; ++nt) {
      int p = r0 + wm * 64 + mt * 16 + q * 4;
      int o = o0 + wn * 32 + nt * 16 + mr;
      int nn = p >> 12, pyx = p & 4095;
      *(f32x4*)(out + ((size_t)(nn * 256 + o) << 12) + pyx) = acc[mt][nt];
    }
}

extern "C" void kernel_launch(void* const* d_in, const int* in_sizes, int n_in,
                              void* d_out, int out_size, void* d_ws, size_t ws_size,
                              hipStream_t stream) {
  const float* x     = (const float*)d_in[0];
  const float* w_off = (const float*)d_in[1];
  const float* b_off = (const float*)d_in[2];
  const float* dcn_w = (const float*)d_in[3];
  float* out = (float*)d_out;
  char* ws = (char*)d_ws;
  unsigned short* xbf   = (unsigned short*)(ws + XBF_OFF);
  unsigned short* wrep  = (unsigned short*)(ws + WREP_OFF);
  unsigned short* wmain = (unsigned short*)(ws + WMAIN_OFF);
  float*          om    = (float*)(ws + OM_OFF);

  k_transpose<<<dim3(64, 8, 4), 256, 0, stream>>>(x, xbf);
  k_repack<<<(288 * 2304) / 256, 256, 0, stream>>>(w_off, dcn_w, wrep, wmain);
  k_offconv<<<256, 256, 0, stream>>>(xbf, wrep, b_off, om);
  k_gemm_fused<<<dim3(128, 2), 512, 0, stream>>>(xbf, om, wmain, out);
}

// Round 5
// 138.442 us; speedup vs baseline: 1.7000x; 1.2074x over previous
//
#include <hip/hip_runtime.h>

// DCNv2 forward, MI355X (gfx950).
//  k_transpose:  x NCHW f32 -> x_bf NHWC bf16
//  k_repack:     both weight tensors -> [oc][kk*256+c] bf16
//  k_offconv:    implicit-im2col MFMA GEMM -> om[r][32] f32 (bias+sigmoid).
//                512 thr, K-split-2 across wave groups, BK=64, reg prefetch.
//  k_gemm_fused: deformable-im2col fused GEMM. 1024 thr = 16 waves (4/SIMD):
//                waves 0-7 K-half 0, waves 8-15 K-half 1; per-group LDS tiles
//                (XOR-swizzled, single-buffered, 2 barriers/iter, reg prefetch);
//                LDS reduction of the two K-partials in the epilogue.

typedef __bf16 bf16x8 __attribute__((ext_vector_type(8)));
typedef float  f32x4  __attribute__((ext_vector_type(4)));
typedef unsigned short ushort8 __attribute__((ext_vector_type(8)));

#define XBF_OFF   0u            // 4*4096*256*2  = 8,388,608
#define WREP_OFF  8388608u      // 32*2304*2     =   147,456
#define WMAIN_OFF 8536064u      // 256*2304*2    = 1,179,648
#define OM_OFF    9715712u      // 16384*32*4    = 2,097,152

__device__ __forceinline__ unsigned short f2bf(float f) {
  unsigned int u = __float_as_uint(f);
  u += 0x7fffu + ((u >> 16) & 1u);
  return (unsigned short)(u >> 16);
}
__device__ __forceinline__ float bf2f(unsigned short h) {
  return __uint_as_float(((unsigned int)h) << 16);
}

// ---------------- x NCHW -> NHWC bf16 ----------------
__global__ __launch_bounds__(256) void k_transpose(const float* __restrict__ x,
                                                   unsigned short* __restrict__ xbf) {
  __shared__ float tile[32][65];
  int n  = blockIdx.z;
  int cb = blockIdx.y;
  int xb = blockIdx.x;
  int t  = threadIdx.x;
  int xx  = t & 63;
  int cc0 = t >> 6;
#pragma unroll
  for (int j = 0; j < 8; ++j) {
    int cc = cc0 + j * 4;
    tile[cc][xx] = x[((size_t)(n * 256 + cb * 32 + cc) << 12) + xb * 64 + xx];
  }
  __syncthreads();
  int ccw = t & 31;
  int xw0 = t >> 5;
#pragma unroll
  for (int j = 0; j < 8; ++j) {
    int xw = xw0 + j * 8;
    xbf[((size_t)((n << 12) + xb * 64 + xw)) * 256 + cb * 32 + ccw] = f2bf(tile[ccw][xw]);
  }
}

// ---------------- weight repack ----------------
__global__ __launch_bounds__(256) void k_repack(const float* __restrict__ w_off,
                                                const float* __restrict__ dcn_w,
                                                unsigned short* __restrict__ wrep,
                                                unsigned short* __restrict__ wmain) {
  int idx = blockIdx.x * 256 + threadIdx.x;
  if (idx < 32 * 2304) {
    int oc  = idx / 2304;
    int rem = idx - oc * 2304;
    int kk  = rem >> 8;
    int c   = rem & 255;
    wrep[idx] = f2bf((oc < 27) ? w_off[oc * 2304 + c * 9 + kk] : 0.f);
  } else {
    int j = idx - 32 * 2304;
    int oc  = j / 2304;
    int rem = j - oc * 2304;
    int kk  = rem >> 8;
    int c   = rem & 255;
    wmain[j] = f2bf(dcn_w[oc * 2304 + c * 9 + kk]);
  }
}

// ---------------- offset-field conv: K-split-2, BK=64, 512 threads ----------------
// M-tile 64 rows, N=32, K=2304 -> 36 ksteps of 64; group g (waves 0-3 / 4-7)
// handles ksteps [g*18, g*18+18). Epilogue reduces the two partials via LDS.
__global__ __launch_bounds__(512) void k_offconv(const unsigned short* __restrict__ xbf,
                                                 const unsigned short* __restrict__ wrep,
                                                 const float* __restrict__ bias,
                                                 float* __restrict__ om) {
  // SH layout: [0..2][group]: A tiles 2*(64*64), B tiles 2*(32*64); floats scratch aliases.
  __shared__ __align__(16) unsigned short SHa[2][64 * 64];
  __shared__ __align__(16) unsigned short SHb[2][32 * 64];
  int t = threadIdx.x;
  int wave = t >> 6, lane = t & 63;
  int grp = wave >> 2, wv = wave & 3;
  int tg = t & 255;
  int bm = ((blockIdx.x & 7) << 5) + (blockIdx.x >> 3);   // XCD swizzle
  int n = bm >> 6, oy = bm & 63;

  unsigned short* As = SHa[grp];
  unsigned short* Bs = SHb[grp];

  // A role: row 0..63, two 8-ch chunks; B role: row 0..31, one 8-ch chunk
  int arow = tg >> 2, acc4 = tg & 3;          // chunk base cc = acc4 (16 ch)
  int brow = tg >> 3, bch = tg & 7;

  f32x4 acc0 = {0.f, 0.f, 0.f, 0.f};
  f32x4 acc1 = {0.f, 0.f, 0.f, 0.f};

  ushort8 av[2]; ushort8 bv;
  auto prefetch = [&](int ktg) {
    int kk = ktg >> 2;
    int c0 = (ktg & 3) * 64;
    int dy = kk / 3 - 1, dx = kk % 3 - 1;
    int yy = oy + dy, xxg = arow + dx;
    bool ok = ((unsigned)yy < 64u) && ((unsigned)xxg < 64u);
    const unsigned short* p = xbf + (size_t)(((n * 64 + yy) * 64 + xxg) * 256 + c0 + acc4 * 16);
#pragma unroll
    for (int g = 0; g < 2; ++g)
      av[g] = ok ? *(const ushort8*)(p + g * 8) : (ushort8){0,0,0,0,0,0,0,0};
    bv = *(const ushort8*)(wrep + (size_t)brow * 2304 + ktg * 64 + bch * 8);
  };

  prefetch(grp * 18);
  int mr = lane & 15, q = lane >> 4;
  for (int kt = 0; kt < 18; ++kt) {
    __syncthreads();
#pragma unroll
    for (int g = 0; g < 2; ++g) {
      int ch = (acc4 * 2 + g) ^ (arow & 7);
      *(ushort8*)&As[arow * 64 + ch * 8] = av[g];
    }
    { int ch = bch ^ (brow & 7);
      *(ushort8*)&Bs[brow * 64 + ch * 8] = bv; }
    __syncthreads();
    if (kt < 17) prefetch(grp * 18 + kt + 1);
#pragma unroll
    for (int kh = 0; kh < 2; ++kh) {
      int coff = ((q + kh * 4) ^ (mr & 7)) * 8;
      bf16x8 a  = *(const bf16x8*)&As[(wv * 16 + mr) * 64 + coff];
      bf16x8 b0 = *(const bf16x8*)&Bs[mr * 64 + coff];
      bf16x8 b1 = *(const bf16x8*)&Bs[(16 + mr) * 64 + coff];
      acc0 = __builtin_amdgcn_mfma_f32_16x16x32_bf16(a, b0, acc0, 0, 0, 0);
      acc1 = __builtin_amdgcn_mfma_f32_16x16x32_bf16(a, b1, acc1, 0, 0, 0);
    }
  }
  // reduce group 1 into group 0 via LDS (aliases SHa: need 64*32*4 = 8 KB <= 16 KB)
  float* scratch = (float*)&SHa[0][0];
  __syncthreads();
  if (grp == 1) {
#pragma unroll
    for (int nt = 0; nt < 2; ++nt) {
      f32x4 a = nt ? acc1 : acc0;
#pragma unroll
      for (int rg = 0; rg < 4; ++rg)
        scratch[(wv * 16 + q * 4 + rg) * 32 + nt * 16 + mr] = a[rg];
    }
  }
  __syncthreads();
  if (grp == 0) {
    int r0 = bm * 64;
#pragma unroll
    for (int nt = 0; nt < 2; ++nt) {
      f32x4 a = nt ? acc1 : acc0;
      int oc = nt * 16 + mr;
      float bvl = (oc < 27) ? bias[oc] : 0.f;
#pragma unroll
      for (int rg = 0; rg < 4; ++rg) {
        int pl = wv * 16 + q * 4 + rg;
        float v = a[rg] + scratch[pl * 32 + oc] + bvl;
        if (oc >= 18 && oc < 27) v = 1.f / (1.f + __expf(-v));
        om[(r0 + pl) * 32 + oc] = v;
      }
    }
  }
}

// ---------------- fused deformable-im2col GEMM, K-split-2, 1024 threads ------
__global__ __launch_bounds__(1024) void k_gemm_fused(const unsigned short* __restrict__ xbf,
                                                     const float* __restrict__ om,
                                                     const unsigned short* __restrict__ wB,
                                                     float* __restrict__ out) {
  __shared__ __align__(16) unsigned short SH[4][128 * 64];  // [A g0][A g1][B g0][B g1]; 64 KB
  int t = threadIdx.x;
  int wave = t >> 6, lane = t & 63;
  int grp = wave >> 3, wv = wave & 7;
  int wm = wv & 1, wn = wv >> 1;
  int tg = t & 511;
  int bmx = ((blockIdx.x & 7) << 4) + (blockIdx.x >> 3);    // XCD swizzle
  int r0 = bmx * 128, o0 = blockIdx.y * 128;

  unsigned short* As = SH[grp];
  unsigned short* Bs = SH[2 + grp];

  // sampling role: row 0..127, 16 channels (two 8-ch chunks)
  int srow = tg >> 2, sc4 = tg & 3;
  int r = r0 + srow;
  int n = r >> 12, yx = r & 4095, oy = yx >> 6, ox = yx & 63;
  const unsigned short* xb = xbf + (size_t)n * (4096 * 256);
  const float* omr = om + (size_t)r * 32;

  // B role: row 0..127, 16 k (two 8 chunks)
  const unsigned short* Bg = wB + (size_t)(o0 + srow) * 2304 + sc4 * 16;

  f32x4 acc[4][2];
#pragma unroll
  for (int mt = 0; mt < 4; ++mt)
#pragma unroll
    for (int nt = 0; nt < 2; ++nt) acc[mt][nt] = (f32x4){0.f, 0.f, 0.f, 0.f};

  float w1, w2, w3, w4;
  int a1, a2, a3, a4;
  auto params = [&](int kk) {
    float offy = omr[2 * kk], offx = omr[2 * kk + 1], m = omr[18 + kk];
    float py = (float)(oy + kk / 3) + offy;
    float px = (float)(ox + kk % 3) + offx;
    py = fminf(fmaxf(py, 0.f), 65.f);
    px = fminf(fmaxf(px, 0.f), 65.f);
    float fy = floorf(py), fx = floorf(px);
    float ly = py - fy, lx = px - fx;
    float hy = 1.f - ly, hx = 1.f - lx;
    int iy = (int)fy, ix = (int)fx;
    bool yv0 = (iy >= 1) && (iy <= 64);
    bool yv1 = (iy <= 63);
    bool xv0 = (ix >= 1) && (ix <= 64);
    bool xv1 = (ix <= 63);
    int y0 = min(max(iy - 1, 0), 63);
    int y1 = min(iy, 63);
    int x0 = min(max(ix - 1, 0), 63);
    int x1 = min(ix, 63);
    w1 = (yv0 && xv0) ? hy * hx * m : 0.f;
    w2 = (yv0 && xv1) ? hy * lx * m : 0.f;
    w3 = (yv1 && xv0) ? ly * hx * m : 0.f;
    w4 = (yv1 && xv1) ? ly * lx * m : 0.f;
    a1 = ((y0 << 6) + x0) * 256;
    a2 = ((y0 << 6) + x1) * 256;
    a3 = ((y1 << 6) + x0) * 256;
    a4 = ((y1 << 6) + x1) * 256;
  };

  ushort8 g1[2], g2[2], g3[2], g4[2], bv[2];
  auto prefetch = [&](int ktg) {
    int c0 = (ktg & 3) * 64 + sc4 * 16;
#pragma unroll
    for (int g = 0; g < 2; ++g) {
      int c = c0 + g * 8;
      g1[g] = *(const ushort8*)(xb + a1 + c);
      g2[g] = *(const ushort8*)(xb + a2 + c);
      g3[g] = *(const ushort8*)(xb + a3 + c);
      g4[g] = *(const ushort8*)(xb + a4 + c);
      bv[g] = *(const ushort8*)(Bg + ktg * 64 + g * 8);
    }
  };

  params((grp * 18) >> 2);
  prefetch(grp * 18);

  int mr = lane & 15, q = lane >> 4;
  for (int kt = 0; kt < 18; ++kt) {
    int ktg = grp * 18 + kt;
    // blend (waits on prefetched gathers)
    ushort8 res[2];
#pragma unroll
    for (int g = 0; g < 2; ++g) {
#pragma unroll
      for (int j = 0; j < 8; ++j) {
        float v = w1 * bf2f(g1[g][j]) + w2 * bf2f(g2[g][j]) +
                  w3 * bf2f(g3[g][j]) + w4 * bf2f(g4[g][j]);
        res[g][j] = f2bf(v);
      }
    }
    __syncthreads();                           // prev MFMA reads done
#pragma unroll
    for (int g = 0; g < 2; ++g) {
      int ch = (sc4 * 2 + g) ^ (srow & 7);
      *(ushort8*)&As[srow * 64 + ch * 8] = res[g];
      *(ushort8*)&Bs[srow * 64 + ch * 8] = bv[g];
    }
    __syncthreads();                           // writes visible
    if (kt < 17) {
      int nktg = ktg + 1;
      if ((nktg & 3) == 0) params(nktg >> 2);
      prefetch(nktg);                          // covered by MFMA phase below
    }
#pragma unroll
    for (int kh = 0; kh < 2; ++kh) {
      int coff = ((q + kh * 4) ^ (mr & 7)) * 8;
      bf16x8 af[4], bfv[2];
#pragma unroll
      for (int mt = 0; mt < 4; ++mt)
        af[mt] = *(const bf16x8*)&As[(wm * 64 + mt * 16 + mr) * 64 + coff];
#pragma unroll
      for (int nt = 0; nt < 2; ++nt)
        bfv[nt] = *(const bf16x8*)&Bs[(wn * 32 + nt * 16 + mr) * 64 + coff];
#pragma unroll
      for (int mt = 0; mt < 4; ++mt)
#pragma unroll
        for (int nt = 0; nt < 2; ++nt)
          acc[mt][nt] = __builtin_amdgcn_mfma_f32_16x16x32_bf16(af[mt], bfv[nt], acc[mt][nt], 0, 0, 0);
    }
  }

  // reduce K-partials: grp1 -> LDS (64 KB scratch = whole SH), grp0 adds + stores
  float* scratch = (float*)&SH[0][0];
  __syncthreads();
  if (grp == 1) {
#pragma unroll
    for (int mt = 0; mt < 4; ++mt)
#pragma unroll
      for (int nt = 0; nt < 2; ++nt) {
        int pl = wm * 64 + mt * 16 + q * 4;
        int ol = wn * 32 + nt * 16 + mr;
#pragma unroll
        for (int rg = 0; rg < 4; ++rg)
          scratch[(pl + rg) * 128 + ol] = acc[mt][nt][rg];
      }
  }
  __syncthreads();
  if (grp == 0) {
#pragma unroll
    for (int mt = 0; mt < 4; ++mt)
#pragma unroll
      for (int nt = 0; nt < 2; ++nt) {
        int pl = wm * 64 + mt * 16 + q * 4;
        int ol = wn * 32 + nt * 16 + mr;
        f32x4 v = acc[mt][nt];
#pragma unroll
        for (int rg = 0; rg < 4; ++rg) v[rg] += scratch[(pl + rg) * 128 + ol];
        int p = r0 + pl;
        int o = o0 + ol;
        int nn = p >> 12, pyx = p & 4095;
        *(f32x4*)(out + ((size_t)(nn * 256 + o) << 12) + pyx) = v;
      }
  }
}

extern "C" void kernel_launch(void* const* d_in, const int* in_sizes, int n_in,
                              void* d_out, int out_size, void* d_ws, size_t ws_size,
                              hipStream_t stream) {
  const float* x     = (const float*)d_in[0];
  const float* w_off = (const float*)d_in[1];
  const float* b_off = (const float*)d_in[2];
  const float* dcn_w = (const float*)d_in[3];
  float* out = (float*)d_out;
  char* ws = (char*)d_ws;
  unsigned short* xbf   = (unsigned short*)(ws + XBF_OFF);
  unsigned short* wrep  = (unsigned short*)(ws + WREP_OFF);
  unsigned short* wmain = (unsigned short*)(ws + WMAIN_OFF);
  float*          om    = (float*)(ws + OM_OFF);

  k_transpose<<<dim3(64, 8, 4), 256, 0, stream>>>(x, xbf);
  k_repack<<<(288 * 2304) / 256, 256, 0, stream>>>(w_off, dcn_w, wrep, wmain);
  k_offconv<<<256, 512, 0, stream>>>(xbf, wrep, b_off, om);
  k_gemm_fused<<<dim3(128, 2), 1024, 0, stream>>>(xbf, om, wmain, out);
}

// Round 6
// 134.663 us; speedup vs baseline: 1.7477x; 1.0281x over previous
//
#include <hip/hip_runtime.h>

// DCNv2 forward, MI355X (gfx950).
//  k_pre:        (merged) x NCHW f32 -> xbf NHWC bf16  +  weight repack
//  k_offconv:    implicit-im2col MFMA GEMM -> om[r][32] f32 (bias+sigmoid).
//                512 thr, K-split-2, BK=64, depth-2 reg prefetch, RAW barriers.
//  k_gemm_fused: deformable-im2col fused GEMM. 1024 thr = 16 waves (4/SIMD),
//                K-split-2 wave groups, XOR-swizzled LDS, RAW barriers
//                (s_waitcnt lgkmcnt(0) only — gathers stay in flight across
//                barriers, unlike __syncthreads' vmcnt(0) drain), perm-packed
//                bf16 blend, LDS reduction of K-partials.

typedef __bf16 bf16x8 __attribute__((ext_vector_type(8)));
typedef float  f32x4  __attribute__((ext_vector_type(4)));
typedef unsigned short ushort8 __attribute__((ext_vector_type(8)));
typedef unsigned int   uint4v  __attribute__((ext_vector_type(4)));

#define XBF_OFF   0u            // 4*4096*256*2  = 8,388,608
#define WREP_OFF  8388608u      // 32*2304*2     =   147,456
#define WMAIN_OFF 8536064u      // 256*2304*2    = 1,179,648
#define OM_OFF    9715712u      // 16384*32*4    = 2,097,152

// wait lgkmcnt(0) only (vmcnt(63)=no wait, expcnt(7)=no wait), then barrier.
#define LGKM0_BAR() do { __builtin_amdgcn_s_waitcnt(0xC07F); __builtin_amdgcn_s_barrier(); } while (0)

__device__ __forceinline__ unsigned short f2bf(float f) {
  unsigned int u = __float_as_uint(f);
  u += 0x7fffu + ((u >> 16) & 1u);
  return (unsigned short)(u >> 16);
}
__device__ __forceinline__ float bf2f(unsigned short h) {
  return __uint_as_float(((unsigned int)h) << 16);
}

// ---------------- merged transpose + repack ----------------
__global__ __launch_bounds__(256) void k_pre(const float* __restrict__ x,
                                             const float* __restrict__ w_off,
                                             const float* __restrict__ dcn_w,
                                             unsigned short* __restrict__ xbf,
                                             unsigned short* __restrict__ wrep,
                                             unsigned short* __restrict__ wmain) {
  __shared__ float tile[32][65];
  int b = blockIdx.x;
  int t = threadIdx.x;
  if (b < 2048) {               // transpose role
    int n  = b >> 9;
    int cb = (b >> 6) & 7;
    int xb = b & 63;
    int xx  = t & 63;
    int cc0 = t >> 6;
#pragma unroll
    for (int j = 0; j < 8; ++j) {
      int cc = cc0 + j * 4;
      tile[cc][xx] = x[((size_t)(n * 256 + cb * 32 + cc) << 12) + xb * 64 + xx];
    }
    __syncthreads();
    int ccw = t & 31;
    int xw0 = t >> 5;
#pragma unroll
    for (int j = 0; j < 8; ++j) {
      int xw = xw0 + j * 8;
      xbf[((size_t)((n << 12) + xb * 64 + xw)) * 256 + cb * 32 + ccw] = f2bf(tile[ccw][xw]);
    }
  } else {                      // repack role
    int idx = (b - 2048) * 256 + t;
    if (idx < 32 * 2304) {
      int oc  = idx / 2304;
      int rem = idx - oc * 2304;
      int kk  = rem >> 8;
      int c   = rem & 255;
      wrep[idx] = f2bf((oc < 27) ? w_off[oc * 2304 + c * 9 + kk] : 0.f);
    } else {
      int j = idx - 32 * 2304;
      int oc  = j / 2304;
      int rem = j - oc * 2304;
      int kk  = rem >> 8;
      int c   = rem & 255;
      wmain[j] = f2bf(dcn_w[oc * 2304 + c * 9 + kk]);
    }
  }
}

// ---------------- offset-field conv: K-split-2, BK=64, depth-2 prefetch ------
__global__ __launch_bounds__(512) void k_offconv(const unsigned short* __restrict__ xbf,
                                                 const unsigned short* __restrict__ wrep,
                                                 const float* __restrict__ bias,
                                                 float* __restrict__ om) {
  __shared__ __align__(16) unsigned short SHa[2][64 * 64];
  __shared__ __align__(16) unsigned short SHb[2][32 * 64];
  int t = threadIdx.x;
  int wave = t >> 6, lane = t & 63;
  int grp = wave >> 2, wv = wave & 3;
  int tg = t & 255;
  int bm = ((blockIdx.x & 7) << 5) + (blockIdx.x >> 3);   // XCD swizzle
  int n = bm >> 6, oy = bm & 63;

  unsigned short* As = SHa[grp];
  unsigned short* Bs = SHb[grp];

  int arow = tg >> 2, acc4 = tg & 3;
  int brow = tg >> 3, bch = tg & 7;

  f32x4 acc0 = {0.f, 0.f, 0.f, 0.f};
  f32x4 acc1 = {0.f, 0.f, 0.f, 0.f};

  ushort8 av[2][2]; ushort8 bv[2];
  auto prefetch = [&](int ktg, int slot) {
    int kk = ktg >> 2;
    int c0 = (ktg & 3) * 64;
    int dy = kk / 3 - 1, dx = kk % 3 - 1;
    int yy = oy + dy, xxg = arow + dx;
    bool ok = ((unsigned)yy < 64u) && ((unsigned)xxg < 64u);
    const unsigned short* p = xbf + (size_t)(((n * 64 + yy) * 64 + xxg) * 256 + c0 + acc4 * 16);
#pragma unroll
    for (int g = 0; g < 2; ++g)
      av[slot][g] = ok ? *(const ushort8*)(p + g * 8) : (ushort8){0,0,0,0,0,0,0,0};
    bv[slot] = *(const ushort8*)(wrep + (size_t)brow * 2304 + ktg * 64 + bch * 8);
  };

  int k0 = grp * 18;
  prefetch(k0, 0);
  prefetch(k0 + 1, 1);
  int mr = lane & 15, q = lane >> 4;
  for (int kt = 0; kt < 18; ++kt) {
    int slot = kt & 1;
    LGKM0_BAR();
#pragma unroll
    for (int g = 0; g < 2; ++g) {
      int ch = (acc4 * 2 + g) ^ (arow & 7);
      *(ushort8*)&As[arow * 64 + ch * 8] = av[slot][g];
    }
    { int ch = bch ^ (brow & 7);
      *(ushort8*)&Bs[brow * 64 + ch * 8] = bv[slot]; }
    if (kt + 2 < 18) prefetch(k0 + kt + 2, slot);
    LGKM0_BAR();
#pragma unroll
    for (int kh = 0; kh < 2; ++kh) {
      int coff = ((q + kh * 4) ^ (mr & 7)) * 8;
      bf16x8 a  = *(const bf16x8*)&As[(wv * 16 + mr) * 64 + coff];
      bf16x8 b0 = *(const bf16x8*)&Bs[mr * 64 + coff];
      bf16x8 b1 = *(const bf16x8*)&Bs[(16 + mr) * 64 + coff];
      acc0 = __builtin_amdgcn_mfma_f32_16x16x32_bf16(a, b0, acc0, 0, 0, 0);
      acc1 = __builtin_amdgcn_mfma_f32_16x16x32_bf16(a, b1, acc1, 0, 0, 0);
    }
  }
  float* scratch = (float*)&SHa[0][0];
  __syncthreads();
  if (grp == 1) {
#pragma unroll
    for (int nt = 0; nt < 2; ++nt) {
      f32x4 a = nt ? acc1 : acc0;
#pragma unroll
      for (int rg = 0; rg < 4; ++rg)
        scratch[(wv * 16 + q * 4 + rg) * 32 + nt * 16 + mr] = a[rg];
    }
  }
  __syncthreads();
  if (grp == 0) {
    int r0 = bm * 64;
#pragma unroll
    for (int nt = 0; nt < 2; ++nt) {
      f32x4 a = nt ? acc1 : acc0;
      int oc = nt * 16 + mr;
      float bvl = (oc < 27) ? bias[oc] : 0.f;
#pragma unroll
      for (int rg = 0; rg < 4; ++rg) {
        int pl = wv * 16 + q * 4 + rg;
        float v = a[rg] + scratch[pl * 32 + oc] + bvl;
        if (oc >= 18 && oc < 27) v = 1.f / (1.f + __expf(-v));
        om[(r0 + pl) * 32 + oc] = v;
      }
    }
  }
}

// ---------------- fused deformable-im2col GEMM, raw-barrier pipeline ----------
__global__ __launch_bounds__(1024) void k_gemm_fused(const unsigned short* __restrict__ xbf,
                                                     const float* __restrict__ om,
                                                     const unsigned short* __restrict__ wB,
                                                     float* __restrict__ out) {
  __shared__ __align__(16) unsigned short SH[4][128 * 64];  // [A g0][A g1][B g0][B g1]
  int t = threadIdx.x;
  int wave = t >> 6, lane = t & 63;
  int grp = wave >> 3, wv = wave & 7;
  int wm = wv & 1, wn = wv >> 1;
  int tg = t & 511;
  int bmx = ((blockIdx.x & 7) << 4) + (blockIdx.x >> 3);    // XCD swizzle
  int r0 = bmx * 128, o0 = blockIdx.y * 128;

  unsigned short* As = SH[grp];
  unsigned short* Bs = SH[2 + grp];

  int srow = tg >> 2, sc4 = tg & 3;
  int r = r0 + srow;
  int n = r >> 12, yx = r & 4095, oy = yx >> 6, ox = yx & 63;
  const unsigned short* xb = xbf + (size_t)n * (4096 * 256);
  const float* omr = om + (size_t)r * 32;
  const unsigned short* Bg = wB + (size_t)(o0 + srow) * 2304 + sc4 * 16;

  f32x4 acc[4][2];
#pragma unroll
  for (int mt = 0; mt < 4; ++mt)
#pragma unroll
    for (int nt = 0; nt < 2; ++nt) acc[mt][nt] = (f32x4){0.f, 0.f, 0.f, 0.f};

  float w1, w2, w3, w4;
  int a1, a2, a3, a4;
  auto params = [&](int kk) {
    float offy = omr[2 * kk], offx = omr[2 * kk + 1], m = omr[18 + kk];
    float py = (float)(oy + kk / 3) + offy;
    float px = (float)(ox + kk % 3) + offx;
    py = fminf(fmaxf(py, 0.f), 65.f);
    px = fminf(fmaxf(px, 0.f), 65.f);
    float fy = floorf(py), fx = floorf(px);
    float ly = py - fy, lx = px - fx;
    float hy = 1.f - ly, hx = 1.f - lx;
    int iy = (int)fy, ix = (int)fx;
    bool yv0 = (iy >= 1) && (iy <= 64);
    bool yv1 = (iy <= 63);
    bool xv0 = (ix >= 1) && (ix <= 64);
    bool xv1 = (ix <= 63);
    int y0 = min(max(iy - 1, 0), 63);
    int y1 = min(iy, 63);
    int x0 = min(max(ix - 1, 0), 63);
    int x1 = min(ix, 63);
    w1 = (yv0 && xv0) ? hy * hx * m : 0.f;
    w2 = (yv0 && xv1) ? hy * lx * m : 0.f;
    w3 = (yv1 && xv0) ? ly * hx * m : 0.f;
    w4 = (yv1 && xv1) ? ly * lx * m : 0.f;
    a1 = ((y0 << 6) + x0) * 256;
    a2 = ((y0 << 6) + x1) * 256;
    a3 = ((y1 << 6) + x0) * 256;
    a4 = ((y1 << 6) + x1) * 256;
  };

  ushort8 g1[2], g2[2], g3[2], g4[2], bv[2];
  auto prefA = [&](int ktg) {
    int c0 = (ktg & 3) * 64 + sc4 * 16;
#pragma unroll
    for (int g = 0; g < 2; ++g) {
      int c = c0 + g * 8;
      g1[g] = *(const ushort8*)(xb + a1 + c);
      g2[g] = *(const ushort8*)(xb + a2 + c);
      g3[g] = *(const ushort8*)(xb + a3 + c);
      g4[g] = *(const ushort8*)(xb + a4 + c);
    }
  };
  auto prefB = [&](int ktg) {
#pragma unroll
    for (int g = 0; g < 2; ++g)
      bv[g] = *(const ushort8*)(Bg + ktg * 64 + g * 8);
  };

  int ktg0 = grp * 18;
  params(ktg0 >> 2);
  prefA(ktg0);
  prefB(ktg0);

  int mr = lane & 15, q = lane >> 4;
  for (int kt = 0; kt < 18; ++kt) {
    int ktg = ktg0 + kt;
    // blend + perm-pack (compiler waits vmcnt for the gathers here)
    uint4v rs[2];
#pragma unroll
    for (int g = 0; g < 2; ++g) {
#pragma unroll
      for (int p = 0; p < 4; ++p) {
        float va = w1 * bf2f(g1[g][2 * p])     + w2 * bf2f(g2[g][2 * p]) +
                   w3 * bf2f(g3[g][2 * p])     + w4 * bf2f(g4[g][2 * p]);
        float vb = w1 * bf2f(g1[g][2 * p + 1]) + w2 * bf2f(g2[g][2 * p + 1]) +
                   w3 * bf2f(g3[g][2 * p + 1]) + w4 * bf2f(g4[g][2 * p + 1]);
        unsigned ua = __float_as_uint(va) + 0x8000u;
        unsigned ub = __float_as_uint(vb) + 0x8000u;
        rs[g][p] = __builtin_amdgcn_perm(ub, ua, 0x07060302u);
      }
    }
    // issue next A gathers NOW — they fly across both barriers + MFMA phase
    if (kt < 17) {
      if (((ktg + 1) & 3) == 0) params((ktg + 1) >> 2);
      prefA(ktg + 1);
    }
    LGKM0_BAR();                 // all waves done reading LDS tile kt-1
#pragma unroll
    for (int g = 0; g < 2; ++g) {
      int ch = (sc4 * 2 + g) ^ (srow & 7);
      *(uint4v*)&As[srow * 64 + ch * 8] = rs[g];
      *(ushort8*)&Bs[srow * 64 + ch * 8] = bv[g];
    }
    if (kt < 17) prefB(ktg + 1);
    LGKM0_BAR();                 // writes visible (lgkm drained)
#pragma unroll
    for (int kh = 0; kh < 2; ++kh) {
      int coff = ((q + kh * 4) ^ (mr & 7)) * 8;
      bf16x8 af[4], bfv[2];
#pragma unroll
      for (int mt = 0; mt < 4; ++mt)
        af[mt] = *(const bf16x8*)&As[(wm * 64 + mt * 16 + mr) * 64 + coff];
#pragma unroll
      for (int nt = 0; nt < 2; ++nt)
        bfv[nt] = *(const bf16x8*)&Bs[(wn * 32 + nt * 16 + mr) * 64 + coff];
#pragma unroll
      for (int mt = 0; mt < 4; ++mt)
#pragma unroll
        for (int nt = 0; nt < 2; ++nt)
          acc[mt][nt] = __builtin_amdgcn_mfma_f32_16x16x32_bf16(af[mt], bfv[nt], acc[mt][nt], 0, 0, 0);
    }
  }

  // reduce K-partials through LDS
  float* scratch = (float*)&SH[0][0];
  __syncthreads();
  if (grp == 1) {
#pragma unroll
    for (int mt = 0; mt < 4; ++mt)
#pragma unroll
      for (int nt = 0; nt < 2; ++nt) {
        int pl = wm * 64 + mt * 16 + q * 4;
        int ol = wn * 32 + nt * 16 + mr;
#pragma unroll
        for (int rg = 0; rg < 4; ++rg)
          scratch[(pl + rg) * 128 + ol] = acc[mt][nt][rg];
      }
  }
  __syncthreads();
  if (grp == 0) {
#pragma unroll
    for (int mt = 0; mt < 4; ++mt)
#pragma unroll
      for (int nt = 0; nt < 2; ++nt) {
        int pl = wm * 64 + mt * 16 + q * 4;
        int ol = wn * 32 + nt * 16 + mr;
        f32x4 v = acc[mt][nt];
#pragma unroll
        for (int rg = 0; rg < 4; ++rg) v[rg] += scratch[(pl + rg) * 128 + ol];
        int p = r0 + pl;
        int o = o0 + ol;
        int nn = p >> 12, pyx = p & 4095;
        *(f32x4*)(out + ((size_t)(nn * 256 + o) << 12) + pyx) = v;
      }
  }
}

extern "C" void kernel_launch(void* const* d_in, const int* in_sizes, int n_in,
                              void* d_out, int out_size, void* d_ws, size_t ws_size,
                              hipStream_t stream) {
  const float* x     = (const float*)d_in[0];
  const float* w_off = (const float*)d_in[1];
  const float* b_off = (const float*)d_in[2];
  const float* dcn_w = (const float*)d_in[3];
  float* out = (float*)d_out;
  char* ws = (char*)d_ws;
  unsigned short* xbf   = (unsigned short*)(ws + XBF_OFF);
  unsigned short* wrep  = (unsigned short*)(ws + WREP_OFF);
  unsigned short* wmain = (unsigned short*)(ws + WMAIN_OFF);
  float*          om    = (float*)(ws + OM_OFF);

  k_pre<<<2048 + 2592, 256, 0, stream>>>(x, w_off, dcn_w, xbf, wrep, wmain);
  k_offconv<<<256, 512, 0, stream>>>(xbf, wrep, b_off, om);
  k_gemm_fused<<<dim3(128, 2), 1024, 0, stream>>>(xbf, om, wmain, out);
}